// Round 1
// 149.968 us; speedup vs baseline: 1.3108x; 1.3108x over previous
//
#include <hip/hip_runtime.h>
#include <math.h>

// Problem constants
#define BATCH 4096
#define NFEAT 26
#define VOCAB 10000
#define EDIM 64
#define D0 1664          // NFEAT*EDIM
#define NUMB 13
#define IN_DIM 1677      // D0 + NUMB
#define H1D 1024
#define H2D 512
#define H3D 256
#define EPS 1e-5f

// ---------------------------------------------------------------------------
// KEY INSIGHT: the reference MLP has NO nonlinearity (BN is inference-affine,
// no ReLU). The entire bn0->w1->bn1->w2->bn2->w3->bn3->pred_w chain is one
// affine map:  z_h[row] = [x0;numb] . (u0 * s0) + Cv   with
//   a3 = pw_h * s3            u2 = W3^T a3    (512)
//   a2 = u2  * s2             u1 = W2^T a2    (1024)
//   a1 = u1  * s1             u0 = W1^T a1    (1677)
//   Cv = sum_c pwh*beta3 + sum_p u2*beta2 + sum_n u1*beta1 + sum_j u0*t0
// (s = g*rsqrt(v+EPS), beta = (bias-m)*s + b_bn, t0 = b0 - m0*s0).
// Collapse cost: 2.4 MFLOP. All three GEMMs + H0/H1/H2 round-trips vanish.
// Cross stack stays collapsed to the scalar P/Q recursion (Dots/Csums),
// verified in the previous session.
// ---------------------------------------------------------------------------

// workspace layout (bytes):
//   u2    @     0 : 512 f   (owner-written by collapseA, no zero needed)
//   u1    @  2048 : 1024 f  (atomicAdd in B; zeroed by A)
//   u0    @  6144 : 1792 f  (atomicAdd in C; zeroed by A; 1677 used)
//   Cv    @ 13312 : 1 f     (atomicAdd in B,C; zeroed by A)
//   CvA   @ 13376 : 16 f    (direct-written by A blocks)
//   C3s   @ 13440 : 1 f     (direct-written by A block 16)
//   Csums @ 13456 : 4 f     (direct-written by A block 16)
// zero region = [u1 .. Cv] = floats [512, 3329) -> 2817 floats.

// ---------------------------------------------------------------------------
// collapseA: blocks 0..15 each OWN k-range [bid*32, bid*32+32) of u2:
//   u2[k] = sum_{c<256} a3[c]*W3[c,k]  via 8-way c-split + LDS reduce
//   CvA[bid] = sum_{k in range} u2[k]*beta2[k]   (complete, disjoint)
// block 16: Csums[0..3] (cross/pred column sums) + C3 = sum_c pwh[c]*beta3[c].
// ALL blocks redundantly zero the u1/u0/Cv region (benign: same value 0).
// ---------------------------------------------------------------------------
__global__ __launch_bounds__(256) void collapseA(
    const float* __restrict__ w3, const float* __restrict__ b3,
    const float* __restrict__ bn3, const float* __restrict__ pw,
    const float* __restrict__ b2, const float* __restrict__ bn2,
    const float* __restrict__ cw,
    float* __restrict__ u2, float* __restrict__ CvA,
    float* __restrict__ C3s, float* __restrict__ Csums,
    float* __restrict__ zero_region) {
    const int bid = blockIdx.x, tid = threadIdx.x;
    __shared__ float a3s[H3D];
    __shared__ float part[256];
    __shared__ float red[4][4];

    for (int i = tid; i < 2817; i += 256) zero_region[i] = 0.f;

    if (bid < 16) {
        {   // stage a3 = pw_h * s3 (256 c's, one per thread)
            const int c = tid;
            float s3 = bn3[c] * rsqrtf(bn3[3 * H3D + c] + EPS);
            a3s[c] = pw[D0 + c] * s3;
        }
        __syncthreads();
        const int kk = tid & 31, seg = tid >> 5;
        const int k = bid * 32 + kk;
        float acc = 0.f;
#pragma unroll
        for (int i = 0; i < 32; ++i) {
            int c = seg * 32 + i;
            acc += a3s[c] * w3[(size_t)c * H2D + k];   // coalesced 128B runs
        }
        part[tid] = acc;
        __syncthreads();
        if (tid < 32) {
            float s = 0.f;
#pragma unroll
            for (int sg = 0; sg < 8; ++sg) s += part[sg * 32 + tid];
            const int kq = bid * 32 + tid;
            u2[kq] = s;                                // owner write, no atomic
            float s2 = bn2[kq] * rsqrtf(bn2[3 * H2D + kq] + EPS);
            float beta2 = (b2[kq] - bn2[2 * H2D + kq]) * s2 + bn2[H2D + kq];
            float pc = s * beta2;
            for (int o = 16; o > 0; o >>= 1) pc += __shfl_down(pc, o, 32);
            if (tid == 0) CvA[bid] = pc;
        }
    } else {
        // block 16: Csums + C3
        float p0 = 0.f, p1 = 0.f, p2 = 0.f, p3 = 0.f;
        for (int j = tid; j < D0; j += 256) {
            p0 += cw[j]; p1 += cw[D0 + j]; p2 += cw[2 * D0 + j]; p3 += pw[j];
        }
        for (int o = 32; o > 0; o >>= 1) {
            p0 += __shfl_down(p0, o, 64); p1 += __shfl_down(p1, o, 64);
            p2 += __shfl_down(p2, o, 64); p3 += __shfl_down(p3, o, 64);
        }
        if ((tid & 63) == 0) {
            int w = tid >> 6;
            red[w][0] = p0; red[w][1] = p1; red[w][2] = p2; red[w][3] = p3;
        }
        __syncthreads();
        if (tid < 4) Csums[tid] = red[0][tid] + red[1][tid] + red[2][tid] + red[3][tid];
        __syncthreads();
        float c3;
        {   // 256 threads exactly cover H3D
            const int c = tid;
            float s3 = bn3[c] * rsqrtf(bn3[3 * H3D + c] + EPS);
            c3 = pw[D0 + c] * ((b3[c] - bn3[2 * H3D + c]) * s3 + bn3[H3D + c]);
        }
        for (int o = 32; o > 0; o >>= 1) c3 += __shfl_down(c3, o, 64);
        if ((tid & 63) == 0) red[tid >> 6][0] = c3;
        __syncthreads();
        if (tid == 0) C3s[0] = red[0][0] + red[1][0] + red[2][0] + red[3][0];
    }
}

// ---------------------------------------------------------------------------
// collapseB: 64 blocks = (n-chunk 4 x 256) x (p-chunk 16 x 32).
//   u1[n] += sum_{p in chunk} a2[p]*W2[p,n];  Cv += sum partial_u1[n]*beta1[n]
// (const contribution is linear in the partials -> no extra sync needed).
// block 0 folds CvA[0..15] + C3s into Cv.
// ---------------------------------------------------------------------------
__global__ __launch_bounds__(256) void collapseB(
    const float* __restrict__ w2, const float* __restrict__ bn2,
    const float* __restrict__ u2,
    const float* __restrict__ b1, const float* __restrict__ bn1,
    const float* __restrict__ CvA, const float* __restrict__ C3s,
    float* __restrict__ u1, float* __restrict__ Cv) {
    const int bid = blockIdx.x, tid = threadIdx.x;
    __shared__ float a2s[32];
    __shared__ float red[4];
    const int p0 = (bid >> 2) * 32;
    if (tid < 32) {
        const int p = p0 + tid;
        float s2 = bn2[p] * rsqrtf(bn2[3 * H2D + p] + EPS);
        a2s[tid] = u2[p] * s2;
    }
    __syncthreads();
    const int n = (bid & 3) * 256 + tid;
    float acc = 0.f;
#pragma unroll
    for (int p = 0; p < 32; ++p)
        acc += a2s[p] * w2[(size_t)(p0 + p) * H1D + n];   // coalesced
    atomicAdd(&u1[n], acc);
    float s1 = bn1[n] * rsqrtf(bn1[3 * H1D + n] + EPS);
    float beta1 = (b1[n] - bn1[2 * H1D + n]) * s1 + bn1[H1D + n];
    float pc = acc * beta1;
    for (int o = 32; o > 0; o >>= 1) pc += __shfl_down(pc, o, 64);
    if ((tid & 63) == 0) red[tid >> 6] = pc;
    __syncthreads();
    if (tid == 0) atomicAdd(Cv, red[0] + red[1] + red[2] + red[3]);
    if (bid == 0 && tid < 16) {
        float v = CvA[tid];
        for (int o = 8; o > 0; o >>= 1) v += __shfl_down(v, o, 16);
        if (tid == 0) atomicAdd(Cv, v + C3s[0]);
    }
}

// ---------------------------------------------------------------------------
// collapseC: 112 blocks = (j-chunk 7 x 256) x (n-chunk 16 x 64).
//   u0[j] += sum_{n in chunk} a1[n]*W1[n,j];  Cv += sum partial_u0[j]*t0[j]
// ---------------------------------------------------------------------------
__global__ __launch_bounds__(256) void collapseC(
    const float* __restrict__ w1, const float* __restrict__ bn1,
    const float* __restrict__ u1, const float* __restrict__ bn0,
    float* __restrict__ u0, float* __restrict__ Cv) {
    const int bid = blockIdx.x, tid = threadIdx.x;
    __shared__ float a1s[64];
    __shared__ float red[4];
    const int jc = bid % 7, n0 = (bid / 7) * 64;
    if (tid < 64) {
        const int n = n0 + tid;
        float s1 = bn1[n] * rsqrtf(bn1[3 * H1D + n] + EPS);
        a1s[tid] = u1[n] * s1;
    }
    __syncthreads();
    const int j = jc * 256 + tid;
    float pc = 0.f;
    if (j < IN_DIM) {
        float acc = 0.f;
#pragma unroll 8
        for (int n = 0; n < 64; ++n)
            acc += a1s[n] * w1[(size_t)(n0 + n) * IN_DIM + j];   // coalesced
        atomicAdd(&u0[j], acc);
        float s0 = bn0[j] * rsqrtf(bn0[3 * IN_DIM + j] + EPS);
        float t0 = bn0[IN_DIM + j] - bn0[2 * IN_DIM + j] * s0;
        pc = acc * t0;
    }
    for (int o = 32; o > 0; o >>= 1) pc += __shfl_down(pc, o, 64);
    if ((tid & 63) == 0) red[tid >> 6] = pc;
    __syncthreads();
    if (tid == 0) atomicAdd(Cv, red[0] + red[1] + red[2] + red[3]);
}

// ---------------------------------------------------------------------------
// fuse_out: 512 blocks x 8 rows. Per row: gather emb, 5 dots
// (cw0,cw1,cw2,pw_x from global [L2-hot], v=u0*s0 from LDS), numb dot,
// P/Q cross recursion, sigmoid -> out[b].  Gather/dot loop structure is the
// verified one from the previous session; only the 5th accumulator is new.
// ---------------------------------------------------------------------------
__global__ __launch_bounds__(256) void fuse_out(
    const float* __restrict__ numb, const int* __restrict__ cat,
    const float* __restrict__ emb, const float* __restrict__ bn0,
    const float* __restrict__ cw, const float* __restrict__ cb,
    const float* __restrict__ pw, const float* __restrict__ pb,
    const float* __restrict__ u0, const float* __restrict__ Cv,
    const float* __restrict__ Csums, float* __restrict__ out) {
    __shared__ __align__(16) float vj[IN_DIM + 3];
    __shared__ int idx[8][NFEAT];
    const int bid = blockIdx.x, tid = threadIdx.x;
    const int b0 = bid * 8;

    for (int j = tid; j < IN_DIM; j += 256) {
        float s0 = bn0[j] * rsqrtf(bn0[3 * IN_DIM + j] + EPS);
        vj[j] = u0[j] * s0;
    }
    if (tid < 8 * NFEAT)
        idx[tid / NFEAT][tid % NFEAT] = cat[(b0 + tid / NFEAT) * NFEAT + tid % NFEAT];
    __syncthreads();

    const int wave = tid >> 6, lane = tid & 63;
    const float4* cw0 = (const float4*)cw;
    const float4* cw1 = (const float4*)(cw + D0);
    const float4* cw2 = (const float4*)(cw + 2 * D0);
    const float4* pw4 = (const float4*)pw;

#pragma unroll
    for (int rr = 0; rr < 2; rr++) {
        const int r = wave * 2 + rr, b = b0 + r;
        float d0 = 0.f, d1 = 0.f, d2 = 0.f, dp = 0.f, dv = 0.f;
        for (int j = lane; j < D0 / 4; j += 64) {
            int f = j >> 4, d4 = j & 15;
            float4 v = *(const float4*)&emb[((size_t)f * VOCAB + idx[r][f]) * EDIM + d4 * 4];
            float4 c0 = cw0[j], c1 = cw1[j], c2 = cw2[j], p4 = pw4[j];
            float4 vv = *(const float4*)&vj[j * 4];
            d0 += v.x * c0.x + v.y * c0.y + v.z * c0.z + v.w * c0.w;
            d1 += v.x * c1.x + v.y * c1.y + v.z * c1.z + v.w * c1.w;
            d2 += v.x * c2.x + v.y * c2.y + v.z * c2.z + v.w * c2.w;
            dp += v.x * p4.x + v.y * p4.y + v.z * p4.z + v.w * p4.w;
            dv += v.x * vv.x + v.y * vv.y + v.z * vv.z + v.w * vv.w;
        }
        for (int o = 32; o > 0; o >>= 1) {
            d0 += __shfl_down(d0, o, 64); d1 += __shfl_down(d1, o, 64);
            d2 += __shfl_down(d2, o, 64); dp += __shfl_down(dp, o, 64);
            dv += __shfl_down(dv, o, 64);
        }
        if (lane == 0) {
            float dn = 0.f;
#pragma unroll
            for (int t = 0; t < NUMB; ++t) dn += numb[b * NUMB + t] * vj[D0 + t];
            float P = 1.f, Q = 0.f;
            float dd[3] = {d0, d1, d2};
#pragma unroll
            for (int i = 0; i < 3; i++) {
                float s = 1.f + P * dd[i] + Q * Csums[i];
                P = s * P;
                Q = s * Q + cb[i];
            }
            float z = P * dp + Q * Csums[3] + dv + dn + Cv[0] + pb[0];
            out[b] = 1.f / (1.f + expf(-z));
        }
    }
}

// ---------------------------------------------------------------------------
extern "C" void kernel_launch(void* const* d_in, const int* in_sizes, int n_in,
                              void* d_out, int out_size, void* d_ws, size_t ws_size,
                              hipStream_t stream) {
    const float* numb = (const float*)d_in[0];
    const int* cat = (const int*)d_in[1];
    const float* emb = (const float*)d_in[2];
    const float* bn0 = (const float*)d_in[3];
    const float* w1 = (const float*)d_in[4];
    const float* b1 = (const float*)d_in[5];
    const float* bn1 = (const float*)d_in[6];
    const float* w2 = (const float*)d_in[7];
    const float* b2 = (const float*)d_in[8];
    const float* bn2 = (const float*)d_in[9];
    const float* w3 = (const float*)d_in[10];
    const float* b3 = (const float*)d_in[11];
    const float* bn3 = (const float*)d_in[12];
    const float* cw = (const float*)d_in[13];
    const float* cb = (const float*)d_in[14];
    const float* pw = (const float*)d_in[15];
    const float* pb = (const float*)d_in[16];
    float* out = (float*)d_out;

    char* ws = (char*)d_ws;
    float* u2    = (float*)(ws + 0);      // 512 f
    float* u1    = (float*)(ws + 2048);   // 1024 f
    float* u0    = (float*)(ws + 6144);   // 1792 f (1677 used)
    float* Cv    = (float*)(ws + 13312);  // 1 f
    float* CvA   = (float*)(ws + 13376);  // 16 f
    float* C3s   = (float*)(ws + 13440);  // 1 f
    float* Csums = (float*)(ws + 13456);  // 4 f
    float* zero_region = u1;              // [u1 | u0 | Cv] = 2817 floats

    collapseA<<<17, 256, 0, stream>>>(w3, b3, bn3, pw, b2, bn2, cw,
                                      u2, CvA, C3s, Csums, zero_region);
    collapseB<<<64, 256, 0, stream>>>(w2, bn2, u2, b1, bn1, CvA, C3s, u1, Cv);
    collapseC<<<112, 256, 0, stream>>>(w1, bn1, u1, bn0, u0, Cv);
    fuse_out<<<512, 256, 0, stream>>>(numb, cat, emb, bn0, cw, cb, pw, pb,
                                      u0, Cv, Csums, out);
}